// Round 1
// 193.313 us; speedup vs baseline: 1.0199x; 1.0199x over previous
//
#include <hip/hip_runtime.h>

// Problem constants
#define B_   4
#define C_   256
#define N_   4096   // H*W
#define D_   32     // qk projection dim
#define CP   264    // proj s_x row stride (halves): 256 + 8

typedef _Float16 half8  __attribute__((ext_vector_type(8)));
typedef _Float16 half4v __attribute__((ext_vector_type(4)));
typedef _Float16 half2v __attribute__((ext_vector_type(2)));
typedef float    f32x4  __attribute__((ext_vector_type(4)));

// ---------------------------------------------------------------------------
// Kernel 0: convert W (f32) -> Wh (f16), A-frag layout:
// Wh[((t*8+kc)*16 + row)*32 + kk] = W_t[row][kc*32+kk], t: 0-1 q, 2-3 k, 4-19 v
// ---------------------------------------------------------------------------
__global__ __launch_bounds__(256) void wcvt_kernel(
    const float* __restrict__ Wq, const float* __restrict__ Wk,
    const float* __restrict__ Wv, _Float16* __restrict__ Wh)
{
    const int idx = blockIdx.x * 256 + threadIdx.x;
    const int kk  = idx & 31;
    const int row = (idx >> 5) & 15;
    const int kc  = (idx >> 9) & 7;
    const int t   = idx >> 12;
    const int c   = kc*32 + kk;
    float v;
    if (t < 2)      v = Wq[(t*16 + row)*C_ + c];
    else if (t < 4) v = Wk[((t-2)*16 + row)*C_ + c];
    else            v = Wv[((t-4)*16 + row)*C_ + c];
    Wh[idx] = (_Float16)v;
}

// ---------------------------------------------------------------------------
// Kernel 1: projections. v2: single-barrier full-tile staging.
// X staged once as [n=64][c=256] f16 (rows c-contiguous, +8 pad) so every
// B-frag is ONE ds_read_b128. 1 barrier per block (was 16).
// Outputs: Qh,Kh (B, 4 dchunk, N, 8) f16; Vh2 frag-major for flash:
//   frag F = ((jc>>2)*16 + ctg)*4 + (jc&3), each frag 256 halves
//   (lane' = (jl>>2)*16 + cl, e = jl&3)  -- a flash step's 16 frags are
//   one contiguous 8KB window.
// ---------------------------------------------------------------------------
__global__ __launch_bounds__(256, 2) void proj_kernel(
    const float* __restrict__ sem, const float* __restrict__ str,
    const _Float16* __restrict__ Wh,
    const float* __restrict__ bq, const float* __restrict__ bk,
    const float* __restrict__ bv,
    _Float16* __restrict__ Qh, _Float16* __restrict__ Kh, _Float16* __restrict__ Vh2)
{
    __shared__ __align__(16) _Float16 s_x[64 * CP];   // structural, 33 KB
    __shared__ __align__(16) _Float16 s_s[64 * CP];   // semantic (h==0 only)

    const int bid = blockIdx.x;
    const int h   = bid & 1;
    const int nt6 = (bid >> 1) & 63;
    const int b   = bid >> 7;
    const int n0  = nt6 * 64;
    const int tid = threadIdx.x;
    const int w    = tid >> 6;
    const int lane = tid & 63;
    const int quad = lane >> 4;
    const int l15  = lane & 15;

    const int cnt = (w < 2) ? 3 : 2;
    const int t0  = h*10 + ((w < 2) ? w*3 : 6 + (w-2)*2);
    const bool need_sem = (h == 0);

    f32x4 acc[3][4];
    #pragma unroll
    for (int i = 0; i < 3; ++i)
        #pragma unroll
        for (int j = 0; j < 4; ++j) { acc[i][j][0]=0.f; acc[i][j][1]=0.f; acc[i][j][2]=0.f; acc[i][j][3]=0.f; }

    const size_t xbase = (size_t)b * C_ * N_;

    // ---- stage the whole 64n x 256c tile, then ONE barrier ----
    #pragma unroll
    for (int r = 0; r < 8; ++r) {
        const int slot = r*256 + tid;
        const int nq = slot & 15;        // n-quad (consecutive tid -> coalesced)
        const int cp = slot >> 4;        // c-pair 0..127
        const float* p0 = str + xbase + (size_t)(2*cp) * N_ + n0 + nq*4;
        const float4 a4 = *(const float4*)p0;
        const float4 b4 = *(const float4*)(p0 + N_);
        #pragma unroll
        for (int t = 0; t < 4; ++t) {
            half2v hp; hp[0] = (_Float16)a4[t]; hp[1] = (_Float16)b4[t];
            *(half2v*)(s_x + (nq*4 + t)*CP + 2*cp) = hp;
        }
        if (need_sem) {
            const float* p1 = sem + xbase + (size_t)(2*cp) * N_ + n0 + nq*4;
            const float4 c4 = *(const float4*)p1;
            const float4 d4 = *(const float4*)(p1 + N_);
            #pragma unroll
            for (int t = 0; t < 4; ++t) {
                half2v hp; hp[0] = (_Float16)c4[t]; hp[1] = (_Float16)d4[t];
                *(half2v*)(s_s + (nq*4 + t)*CP + 2*cp) = hp;
            }
        }
    }
    __syncthreads();

    // ---- compute: B-frags are single b128 reads, shared across o-tiles ----
    #pragma unroll 1
    for (int kc = 0; kc < 8; ++kc) {
        half8 bfr[4], sfr[4];
        #pragma unroll
        for (int nt = 0; nt < 4; ++nt)
            bfr[nt] = *(const half8*)(s_x + (nt*16 + l15)*CP + kc*32 + quad*8);
        if (w == 0 && need_sem) {
            #pragma unroll
            for (int nt = 0; nt < 4; ++nt)
                sfr[nt] = *(const half8*)(s_s + (nt*16 + l15)*CP + kc*32 + quad*8);
        }
        #pragma unroll
        for (int mi = 0; mi < 3; ++mi) {
            if (mi >= cnt) break;
            const int t = t0 + mi;
            half8 af = *(const half8*)(Wh + ((size_t)((t*8 + kc)*16 + l15))*32 + quad*8);
            #pragma unroll
            for (int nt = 0; nt < 4; ++nt)
                acc[mi][nt] = __builtin_amdgcn_mfma_f32_16x16x32_f16(
                                  af, (t < 2) ? sfr[nt] : bfr[nt], acc[mi][nt], 0, 0, 0);
        }
    }

    // ---- epilogue: bias, f16 convert, store ----
    #pragma unroll
    for (int mi = 0; mi < 3; ++mi) {
        if (mi >= cnt) break;
        const int t = t0 + mi;
        if (t < 4) {
            const bool isq = (t < 2);
            const int  tt  = isq ? t : (t - 2);
            f32x4 b4 = *(const f32x4*)((isq ? bq : bk) + tt*16 + quad*4);
            _Float16* dst = isq ? Qh : Kh;
            const int dc  = tt*2 + (quad >> 1);
            const int off = (quad & 1) * 4;
            #pragma unroll
            for (int nt = 0; nt < 4; ++nt) {
                const int n = n0 + nt*16 + l15;
                f32x4 a = acc[mi][nt];
                half4v hq;
                hq[0]=(_Float16)(a[0]+b4[0]); hq[1]=(_Float16)(a[1]+b4[1]);
                hq[2]=(_Float16)(a[2]+b4[2]); hq[3]=(_Float16)(a[3]+b4[3]);
                *(half4v*)(dst + ((size_t)(b*4 + dc) * N_ + n) * 8 + off) = hq;
            }
        } else {
            const int ctg = t - 4;                      // global c-tile 0..15
            const int o0  = ctg*16 + quad*4;
            f32x4 b4 = *(const f32x4*)(bv + o0);
            _Float16* vb = Vh2 + (size_t)b * (size_t)N_ * C_;
            #pragma unroll
            for (int nt = 0; nt < 4; ++nt) {
                const int jc = (n0 >> 4) + nt;
                const int F  = ((jc >> 2)*16 + ctg)*4 + (jc & 3);
                const size_t fragb = (size_t)F * 256;
                const int lp = (l15 >> 2) * 16;
                const int e  = l15 & 3;
                f32x4 a = acc[mi][nt];
                #pragma unroll
                for (int r = 0; r < 4; ++r)
                    vb[fragb + (size_t)(lp + quad*4 + r)*4 + e] = (_Float16)(a[r] + b4[r]);
            }
        }
    }
}

// ---------------------------------------------------------------------------
// Kernel 2: flash attention v6 — j-split waves.
// Phase 0 (unchanged): 4 waves split j 4-ways, exact row max via S^T MFMA,
// combined through 512 B of LDS. Main loop: wave w owns j in
// [w*1024, (w+1)*1024) and computes QK^T + exp + P ONCE (was 4x redundant),
// accumulating PV for ALL 256 c (acc[16][2] = 128 VGPRs). V is streamed
// per-c-tile with a 2-deep register double buffer. Epilogue: cross-wave l
// sum + 4-round 32KB LDS accumulator reduction (XOR-swizzled b128 -> no
// extra bank conflicts), each wave stores a c-quarter per round.
// ---------------------------------------------------------------------------
__global__ __launch_bounds__(256, 2) void flash_kernel(
    const _Float16* __restrict__ Qh, const _Float16* __restrict__ Kh,
    const _Float16* __restrict__ Vh2, const float* __restrict__ sem,
    const float* __restrict__ gma, float* __restrict__ out)
{
    __shared__ float s_mp[4*32];
    __shared__ float s_lp[4*32];
    __shared__ __align__(16) float s_red[4][64][32];   // 32 KB

    const int bid = blockIdx.x;
    const int b   = bid >> 7;
    const int i0  = (bid & 127) * 32;
    const int tid = threadIdx.x;
    const int w    = tid >> 6;
    const int lane = tid & 63;
    const int quad = lane >> 4;
    const int l15  = lane & 15;

    // Q B-frags (persistent): B[k=d][n=i]
    const _Float16* qk_base = Qh + (size_t)(b*4 + quad) * N_ * 8;
    const half8 qf0 = *(const half8*)(qk_base + (size_t)(i0 + l15) * 8);
    const half8 qf1 = *(const half8*)(qk_base + (size_t)(i0 + 16 + l15) * 8);

    const _Float16* klane = Kh + ((size_t)(b*4 + quad) * N_ + l15) * 8;
    const _Float16* vbase = Vh2 + (size_t)b * (size_t)N_ * C_ + lane*4;

    // ---- phase 0: exact row max (wave w covers j in [w*1024, w*1024+1024)) ----
    float mx0 = -3e38f, mx1 = -3e38f;
    #pragma unroll 1
    for (int it = 0; it < 16; ++it) {
        const int j0 = w*1024 + it*64;
        #pragma unroll
        for (int js = 0; js < 4; ++js) {
            half8 kf = *(const half8*)(klane + (size_t)(j0 + js*16) * 8);
            f32x4 z; z[0]=0.f; z[1]=0.f; z[2]=0.f; z[3]=0.f;
            f32x4 s0 = __builtin_amdgcn_mfma_f32_16x16x32_f16(kf, qf0, z, 0, 0, 0);
            f32x4 s1 = __builtin_amdgcn_mfma_f32_16x16x32_f16(kf, qf1, z, 0, 0, 0);
            #pragma unroll
            for (int r = 0; r < 4; ++r) { mx0 = fmaxf(mx0, s0[r]); mx1 = fmaxf(mx1, s1[r]); }
        }
    }
    mx0 = fmaxf(mx0, __shfl_xor(mx0, 16)); mx0 = fmaxf(mx0, __shfl_xor(mx0, 32));
    mx1 = fmaxf(mx1, __shfl_xor(mx1, 16)); mx1 = fmaxf(mx1, __shfl_xor(mx1, 32));
    if (lane < 32) s_mp[w*32 + lane] = (lane < 16) ? mx0 : mx1;
    __syncthreads();
    float mf0 = -3e38f, mf1 = -3e38f;
    #pragma unroll
    for (int ww = 0; ww < 4; ++ww) {
        mf0 = fmaxf(mf0, s_mp[ww*32 + l15]);
        mf1 = fmaxf(mf1, s_mp[ww*32 + 16 + l15]);
    }

    // ---- main loop: wave w, j in [w*1024, (w+1)*1024), ALL 256 c ----
    f32x4 acc[16][2];
    #pragma unroll
    for (int ct = 0; ct < 16; ++ct)
        #pragma unroll
        for (int f = 0; f < 2; ++f) { acc[ct][f][0]=0.f; acc[ct][f][1]=0.f; acc[ct][f][2]=0.f; acc[ct][f][3]=0.f; }
    float l0 = 0.f, l1 = 0.f;

    half8 ka[4], kb[4];

    auto kload = [&](half8 (&kf)[4], int j0) {
        #pragma unroll
        for (int js = 0; js < 4; ++js)
            kf[js] = *(const half8*)(klane + (size_t)(j0 + js*16) * 8);
    };

    auto step = [&](const half8 (&kf)[4], half8 (&kfn)[4], int j0, bool more) {
        f32x4 z; z[0]=0.f; z[1]=0.f; z[2]=0.f; z[3]=0.f;
        // S^T for i-frag 0
        f32x4 sf0[4];
        #pragma unroll
        for (int js = 0; js < 4; ++js)
            sf0[js] = __builtin_amdgcn_mfma_f32_16x16x32_f16(kf[js], qf0, z, 0, 0, 0);
        if (more) kload(kfn, j0 + 64);               // K prefetch (next step)

        // exp for i-frag 0 (frees sf0 before sf1 lives)
        half4v pf0[4];
        #pragma unroll
        for (int js = 0; js < 4; ++js) {
            float e0 = __expf(sf0[js][0]-mf0), e1 = __expf(sf0[js][1]-mf0);
            float e2 = __expf(sf0[js][2]-mf0), e3 = __expf(sf0[js][3]-mf0);
            l0 += (e0+e1)+(e2+e3);
            half4v p; p[0]=(_Float16)e0; p[1]=(_Float16)e1; p[2]=(_Float16)e2; p[3]=(_Float16)e3;
            pf0[js] = p;
        }

        // S^T for i-frag 1
        f32x4 sf1[4];
        #pragma unroll
        for (int js = 0; js < 4; ++js)
            sf1[js] = __builtin_amdgcn_mfma_f32_16x16x32_f16(kf[js], qf1, z, 0, 0, 0);

        // V prefetch for c-tile 0 (hidden under exp1)
        const _Float16* vstep = vbase + (size_t)j0 * 256;
        half4v vfa[4], vfb[4];
        #pragma unroll
        for (int js = 0; js < 4; ++js)
            vfa[js] = *(const half4v*)(vstep + js*256);

        half4v pf1[4];
        #pragma unroll
        for (int js = 0; js < 4; ++js) {
            float e0 = __expf(sf1[js][0]-mf1), e1 = __expf(sf1[js][1]-mf1);
            float e2 = __expf(sf1[js][2]-mf1), e3 = __expf(sf1[js][3]-mf1);
            l1 += (e0+e1)+(e2+e3);
            half4v p; p[0]=(_Float16)e0; p[1]=(_Float16)e1; p[2]=(_Float16)e2; p[3]=(_Float16)e3;
            pf1[js] = p;
        }

        // PV over all 16 c-tiles, V double-buffered in registers
        #pragma unroll
        for (int cp = 0; cp < 8; ++cp) {
            const int ca = cp*2, cb = cp*2 + 1;
            #pragma unroll
            for (int js = 0; js < 4; ++js)
                vfb[js] = *(const half4v*)(vstep + (cb*4 + js)*256);
            #pragma unroll
            for (int js = 0; js < 4; ++js) {
                acc[ca][0] = __builtin_amdgcn_mfma_f32_16x16x16f16(vfa[js], pf0[js], acc[ca][0], 0, 0, 0);
                acc[ca][1] = __builtin_amdgcn_mfma_f32_16x16x16f16(vfa[js], pf1[js], acc[ca][1], 0, 0, 0);
            }
            if (cp < 7) {
                #pragma unroll
                for (int js = 0; js < 4; ++js)
                    vfa[js] = *(const half4v*)(vstep + ((cb+1)*4 + js)*256);
            }
            #pragma unroll
            for (int js = 0; js < 4; ++js) {
                acc[cb][0] = __builtin_amdgcn_mfma_f32_16x16x16f16(vfb[js], pf0[js], acc[cb][0], 0, 0, 0);
                acc[cb][1] = __builtin_amdgcn_mfma_f32_16x16x16f16(vfb[js], pf1[js], acc[cb][1], 0, 0, 0);
            }
        }
    };

    kload(ka, w*1024);
    #pragma unroll 1
    for (int s2 = 0; s2 < 8; ++s2) {
        const int j0 = w*1024 + s2*128;
        step(ka, kb, j0, true);
        step(kb, ka, j0 + 64, s2 < 7);
    }

    // ---- epilogue: cross-wave l sum, then 4-round LDS acc reduction ----
    l0 += __shfl_xor(l0, 16); l0 += __shfl_xor(l0, 32);
    l1 += __shfl_xor(l1, 16); l1 += __shfl_xor(l1, 32);
    if (lane < 32) s_lp[w*32 + lane] = (lane < 16) ? l0 : l1;
    __syncthreads();
    float lt0 = 0.f, lt1 = 0.f;
    #pragma unroll
    for (int ww = 0; ww < 4; ++ww) {
        lt0 += s_lp[ww*32 + l15];
        lt1 += s_lp[ww*32 + 16 + l15];
    }
    const float g = gma[0];
    const float sc0 = g / lt0, sc1 = g / lt1;

    const int kx = (lane & 7) << 2;   // XOR swizzle keeps b128 16B-aligned
    #pragma unroll
    for (int rd = 0; rd < 4; ++rd) {
        #pragma unroll
        for (int ctl = 0; ctl < 4; ++ctl) {
            *(f32x4*)&s_red[w][lane][(ctl*8)     ^ kx] = acc[rd*4 + ctl][0];
            *(f32x4*)&s_red[w][lane][(ctl*8 + 4) ^ kx] = acc[rd*4 + ctl][1];
        }
        __syncthreads();
        #pragma unroll
        for (int f = 0; f < 2; ++f) {
            f32x4 r = *(const f32x4*)&s_red[0][lane][(w*8 + f*4) ^ kx];
            #pragma unroll
            for (int ww = 1; ww < 4; ++ww) {
                f32x4 t = *(const f32x4*)&s_red[ww][lane][(w*8 + f*4) ^ kx];
                r[0]+=t[0]; r[1]+=t[1]; r[2]+=t[2]; r[3]+=t[3];
            }
            const float sc = f ? sc1 : sc0;
            const int   ii = i0 + f*16 + l15;
            const int   cb0 = (rd*4 + w)*16 + quad*4;
            #pragma unroll
            for (int r4 = 0; r4 < 4; ++r4) {
                const size_t idx = ((size_t)(b*C_ + cb0 + r4)) * N_ + ii;
                out[idx] = r[r4] * sc + sem[idx];
            }
        }
        if (rd < 3) __syncthreads();
    }
}

extern "C" void kernel_launch(void* const* d_in, const int* in_sizes, int n_in,
                              void* d_out, int out_size, void* d_ws, size_t ws_size,
                              hipStream_t stream) {
    const float* sem = (const float*)d_in[0];
    const float* str = (const float*)d_in[1];
    const float* Wq  = (const float*)d_in[2];
    const float* bq  = (const float*)d_in[3];
    const float* Wk  = (const float*)d_in[4];
    const float* bk  = (const float*)d_in[5];
    const float* Wv  = (const float*)d_in[6];
    const float* bv  = (const float*)d_in[7];
    const float* gma = (const float*)d_in[8];
    float* out = (float*)d_out;

    // Workspace (f16): Qh 1MB | Kh 1MB | Vh2 8MB | Wh 160KB
    _Float16* Qh  = (_Float16*)d_ws;
    _Float16* Kh  = Qh + (size_t)B_*N_*D_;
    _Float16* Vh2 = Kh + (size_t)B_*N_*D_;
    _Float16* Wh  = Vh2 + (size_t)B_*C_*N_;

    hipLaunchKernelGGL(wcvt_kernel, dim3(320), dim3(256), 0, stream, Wq, Wk, Wv, Wh);
    hipLaunchKernelGGL(proj_kernel, dim3(B_*(N_/64)*2), dim3(256), 0, stream,
                       sem, str, Wh, bq, bk, bv, Qh, Kh, Vh2);
    hipLaunchKernelGGL(flash_kernel, dim3(B_*(N_/32)), dim3(256), 0, stream,
                       Qh, Kh, Vh2, sem, gma, out);
}

// Round 2
// 169.934 us; speedup vs baseline: 1.1602x; 1.1376x over previous
//
#include <hip/hip_runtime.h>

// Problem constants
#define B_   4
#define C_   256
#define N_   4096   // H*W
#define D_   32     // qk projection dim
#define CP   264    // proj s_x row stride (halves): 256 + 8

typedef _Float16 half8  __attribute__((ext_vector_type(8)));
typedef _Float16 half4v __attribute__((ext_vector_type(4)));
typedef _Float16 half2v __attribute__((ext_vector_type(2)));
typedef float    f32x4  __attribute__((ext_vector_type(4)));

// ---------------------------------------------------------------------------
// Kernel 0: convert W (f32) -> Wh (f16), A-frag layout:
// Wh[((t*8+kc)*16 + row)*32 + kk] = W_t[row][kc*32+kk], t: 0-1 q, 2-3 k, 4-19 v
// ---------------------------------------------------------------------------
__global__ __launch_bounds__(256) void wcvt_kernel(
    const float* __restrict__ Wq, const float* __restrict__ Wk,
    const float* __restrict__ Wv, _Float16* __restrict__ Wh)
{
    const int idx = blockIdx.x * 256 + threadIdx.x;
    const int kk  = idx & 31;
    const int row = (idx >> 5) & 15;
    const int kc  = (idx >> 9) & 7;
    const int t   = idx >> 12;
    const int c   = kc*32 + kk;
    float v;
    if (t < 2)      v = Wq[(t*16 + row)*C_ + c];
    else if (t < 4) v = Wk[((t-2)*16 + row)*C_ + c];
    else            v = Wv[((t-4)*16 + row)*C_ + c];
    Wh[idx] = (_Float16)v;
}

// ---------------------------------------------------------------------------
// Kernel 1: projections (unchanged except Vh2 layout).
// New Vh2 layout (for flash 16B/lane V loads): for 32-j chunk jc2 = j>>5,
// c-tile ctg, flash-lane lr (0..63), js = (j>>4)&1, e = j&3... element
//   Vh2[b][jc2*8192 + ctg*512 + lr*8 + js*4 + e]
// holds V[c = ctg*16 + (lr&15)][j = jc2*32 + js*16 + (lr>>4)*4 + e]
// so each flash lane reads ONE dwordx4 per c-tile per 32-j step.
// ---------------------------------------------------------------------------
__global__ __launch_bounds__(256, 2) void proj_kernel(
    const float* __restrict__ sem, const float* __restrict__ str,
    const _Float16* __restrict__ Wh,
    const float* __restrict__ bq, const float* __restrict__ bk,
    const float* __restrict__ bv,
    _Float16* __restrict__ Qh, _Float16* __restrict__ Kh, _Float16* __restrict__ Vh2)
{
    __shared__ __align__(16) _Float16 s_x[64 * CP];   // structural, 33 KB
    __shared__ __align__(16) _Float16 s_s[64 * CP];   // semantic (h==0 only)

    const int bid = blockIdx.x;
    const int h   = bid & 1;
    const int nt6 = (bid >> 1) & 63;
    const int b   = bid >> 7;
    const int n0  = nt6 * 64;
    const int tid = threadIdx.x;
    const int w    = tid >> 6;
    const int lane = tid & 63;
    const int quad = lane >> 4;
    const int l15  = lane & 15;

    const int cnt = (w < 2) ? 3 : 2;
    const int t0  = h*10 + ((w < 2) ? w*3 : 6 + (w-2)*2);
    const bool need_sem = (h == 0);

    f32x4 acc[3][4];
    #pragma unroll
    for (int i = 0; i < 3; ++i)
        #pragma unroll
        for (int j = 0; j < 4; ++j) { acc[i][j][0]=0.f; acc[i][j][1]=0.f; acc[i][j][2]=0.f; acc[i][j][3]=0.f; }

    const size_t xbase = (size_t)b * C_ * N_;

    // ---- stage the whole 64n x 256c tile, then ONE barrier ----
    #pragma unroll
    for (int r = 0; r < 8; ++r) {
        const int slot = r*256 + tid;
        const int nq = slot & 15;        // n-quad (consecutive tid -> coalesced)
        const int cp = slot >> 4;        // c-pair 0..127
        const float* p0 = str + xbase + (size_t)(2*cp) * N_ + n0 + nq*4;
        const float4 a4 = *(const float4*)p0;
        const float4 b4 = *(const float4*)(p0 + N_);
        #pragma unroll
        for (int t = 0; t < 4; ++t) {
            half2v hp; hp[0] = (_Float16)a4[t]; hp[1] = (_Float16)b4[t];
            *(half2v*)(s_x + (nq*4 + t)*CP + 2*cp) = hp;
        }
        if (need_sem) {
            const float* p1 = sem + xbase + (size_t)(2*cp) * N_ + n0 + nq*4;
            const float4 c4 = *(const float4*)p1;
            const float4 d4 = *(const float4*)(p1 + N_);
            #pragma unroll
            for (int t = 0; t < 4; ++t) {
                half2v hp; hp[0] = (_Float16)c4[t]; hp[1] = (_Float16)d4[t];
                *(half2v*)(s_s + (nq*4 + t)*CP + 2*cp) = hp;
            }
        }
    }
    __syncthreads();

    // ---- compute: B-frags are single b128 reads, shared across o-tiles ----
    #pragma unroll 1
    for (int kc = 0; kc < 8; ++kc) {
        half8 bfr[4], sfr[4];
        #pragma unroll
        for (int nt = 0; nt < 4; ++nt)
            bfr[nt] = *(const half8*)(s_x + (nt*16 + l15)*CP + kc*32 + quad*8);
        if (w == 0 && need_sem) {
            #pragma unroll
            for (int nt = 0; nt < 4; ++nt)
                sfr[nt] = *(const half8*)(s_s + (nt*16 + l15)*CP + kc*32 + quad*8);
        }
        #pragma unroll
        for (int mi = 0; mi < 3; ++mi) {
            if (mi >= cnt) break;
            const int t = t0 + mi;
            half8 af = *(const half8*)(Wh + ((size_t)((t*8 + kc)*16 + l15))*32 + quad*8);
            #pragma unroll
            for (int nt = 0; nt < 4; ++nt)
                acc[mi][nt] = __builtin_amdgcn_mfma_f32_16x16x32_f16(
                                  af, (t < 2) ? sfr[nt] : bfr[nt], acc[mi][nt], 0, 0, 0);
        }
    }

    // ---- epilogue: bias, f16 convert, store ----
    #pragma unroll
    for (int mi = 0; mi < 3; ++mi) {
        if (mi >= cnt) break;
        const int t = t0 + mi;
        if (t < 4) {
            const bool isq = (t < 2);
            const int  tt  = isq ? t : (t - 2);
            f32x4 b4 = *(const f32x4*)((isq ? bq : bk) + tt*16 + quad*4);
            _Float16* dst = isq ? Qh : Kh;
            const int dc  = tt*2 + (quad >> 1);
            const int off = (quad & 1) * 4;
            #pragma unroll
            for (int nt = 0; nt < 4; ++nt) {
                const int n = n0 + nt*16 + l15;
                f32x4 a = acc[mi][nt];
                half4v hq;
                hq[0]=(_Float16)(a[0]+b4[0]); hq[1]=(_Float16)(a[1]+b4[1]);
                hq[2]=(_Float16)(a[2]+b4[2]); hq[3]=(_Float16)(a[3]+b4[3]);
                *(half4v*)(dst + ((size_t)(b*4 + dc) * N_ + n) * 8 + off) = hq;
            }
        } else {
            const int ctg = t - 4;                      // global c-tile 0..15
            const int o0  = ctg*16 + quad*4;
            f32x4 b4 = *(const f32x4*)(bv + o0);
            _Float16* vb = Vh2 + (size_t)b * (size_t)N_ * C_;
            #pragma unroll
            for (int nt = 0; nt < 4; ++nt) {
                const int jc  = (n0 >> 4) + nt;
                const int jc2 = jc >> 1;
                const int js  = jc & 1;
                const size_t base = (size_t)jc2 * 8192 + (size_t)ctg * 512 + (size_t)js * 4;
                const int lp = (l15 >> 2) * 16;
                const int e  = l15 & 3;
                f32x4 a = acc[mi][nt];
                #pragma unroll
                for (int r = 0; r < 4; ++r)
                    vb[base + (size_t)(lp + quad*4 + r) * 8 + e] = (_Float16)(a[r] + b4[r]);
            }
        }
    }
}

// ---------------------------------------------------------------------------
// Kernel 2: flash attention v7 — (j x c) wave split + full-step prefetch.
// Wave w: wc = w&1 (c-half, 8 c-tiles), wj = w>>1 (j-half, 2048 j).
// acc[8][2] = 64 VGPR; V and K for step t+1 register-double-buffered and
// issued right after step t's QK => ~250+ cyc of cover for L2 latency.
// V loads are 16B/lane (new Vh2 layout). QK/exp are 2x redundant across the
// wc pair (cheap: VALU overlaps MFMA pipe). Epilogue: single-round 2-way
// (wj-pair) LDS reduction + l-sum, 1 barrier.
// ---------------------------------------------------------------------------
__global__ __launch_bounds__(256, 2) void flash_kernel(
    const _Float16* __restrict__ Qh, const _Float16* __restrict__ Kh,
    const _Float16* __restrict__ Vh2, const float* __restrict__ sem,
    const float* __restrict__ gma, float* __restrict__ out)
{
    __shared__ float s_mp[4*32];
    __shared__ float s_lp[4*32];
    __shared__ __align__(16) float s_red[4][64][32];   // 32 KB

    const int bid = blockIdx.x;
    const int b   = bid >> 7;
    const int i0  = (bid & 127) * 32;
    const int tid = threadIdx.x;
    const int w    = tid >> 6;
    const int lane = tid & 63;
    const int quad = lane >> 4;
    const int l15  = lane & 15;
    const int wc   = w & 1;
    const int wj   = w >> 1;

    // Q B-frags (persistent): B[k=d][n=i]
    const _Float16* qk_base = Qh + (size_t)(b*4 + quad) * N_ * 8;
    const half8 qf0 = *(const half8*)(qk_base + (size_t)(i0 + l15) * 8);
    const half8 qf1 = *(const half8*)(qk_base + (size_t)(i0 + 16 + l15) * 8);

    const _Float16* klane = Kh + ((size_t)(b*4 + quad) * N_ + l15) * 8;
    const _Float16* vl    = Vh2 + (size_t)b * (size_t)N_ * C_
                            + (size_t)(wc*8) * 512 + (size_t)lane * 8;

    // ---- phase 0: exact row max (wave w covers j in [w*1024, +1024)), K dbuf ----
    float mx0 = -3e38f, mx1 = -3e38f;
    {
        half8 kp[4], kn[4];
        auto kl4 = [&](half8 (&kf)[4], int j0) {
            #pragma unroll
            for (int js = 0; js < 4; ++js)
                kf[js] = *(const half8*)(klane + (size_t)(j0 + js*16) * 8);
        };
        auto p0step = [&](const half8 (&kf)[4], half8 (&kfn)[4], int j0, bool more) {
            if (more) kl4(kfn, j0 + 64);
            #pragma unroll
            for (int js = 0; js < 4; ++js) {
                f32x4 z; z[0]=0.f; z[1]=0.f; z[2]=0.f; z[3]=0.f;
                f32x4 s0 = __builtin_amdgcn_mfma_f32_16x16x32_f16(kf[js], qf0, z, 0, 0, 0);
                f32x4 s1 = __builtin_amdgcn_mfma_f32_16x16x32_f16(kf[js], qf1, z, 0, 0, 0);
                #pragma unroll
                for (int r = 0; r < 4; ++r) { mx0 = fmaxf(mx0, s0[r]); mx1 = fmaxf(mx1, s1[r]); }
            }
        };
        kl4(kp, w*1024);
        #pragma unroll 1
        for (int it2 = 0; it2 < 8; ++it2) {
            const int j0 = w*1024 + it2*128;
            p0step(kp, kn, j0, true);
            p0step(kn, kp, j0 + 64, it2 < 7);
        }
    }
    mx0 = fmaxf(mx0, __shfl_xor(mx0, 16)); mx0 = fmaxf(mx0, __shfl_xor(mx0, 32));
    mx1 = fmaxf(mx1, __shfl_xor(mx1, 16)); mx1 = fmaxf(mx1, __shfl_xor(mx1, 32));
    if (lane < 32) s_mp[w*32 + lane] = (lane < 16) ? mx0 : mx1;
    __syncthreads();
    float mf0 = -3e38f, mf1 = -3e38f;
    #pragma unroll
    for (int ww = 0; ww < 4; ++ww) {
        mf0 = fmaxf(mf0, s_mp[ww*32 + l15]);
        mf1 = fmaxf(mf1, s_mp[ww*32 + 16 + l15]);
    }

    // ---- main loop: j in [wj*2048, +2048), c-tiles [wc*8, +8) ----
    f32x4 acc[8][2];
    #pragma unroll
    for (int ct = 0; ct < 8; ++ct)
        #pragma unroll
        for (int f = 0; f < 2; ++f) { acc[ct][f][0]=0.f; acc[ct][f][1]=0.f; acc[ct][f][2]=0.f; acc[ct][f][3]=0.f; }
    float l0 = 0.f, l1 = 0.f;

    half8 kA[2], kB[2], vA[8], vB[8];

    auto kl2 = [&](half8 (&kf)[2], int j0) {
        kf[0] = *(const half8*)(klane + (size_t)j0 * 8);
        kf[1] = *(const half8*)(klane + (size_t)(j0 + 16) * 8);
    };
    auto vl8 = [&](half8 (&vf)[8], int j0) {
        const _Float16* p = vl + (size_t)(j0 >> 5) * 8192;
        #pragma unroll
        for (int ct = 0; ct < 8; ++ct)
            vf[ct] = *(const half8*)(p + ct*512);
    };

    auto step = [&](const half8 (&kf)[2], const half8 (&vf)[8],
                    half8 (&kfn)[2], half8 (&vfn)[8], int j0, bool more) {
        f32x4 z; z[0]=0.f; z[1]=0.f; z[2]=0.f; z[3]=0.f;
        f32x4 sf0[2], sf1[2];
        #pragma unroll
        for (int js = 0; js < 2; ++js) {
            sf0[js] = __builtin_amdgcn_mfma_f32_16x16x32_f16(kf[js], qf0, z, 0, 0, 0);
            sf1[js] = __builtin_amdgcn_mfma_f32_16x16x32_f16(kf[js], qf1, z, 0, 0, 0);
        }
        if (more) {                       // full-step-ahead prefetch
            kl2(kfn, j0 + 32);
            vl8(vfn, j0 + 32);
        }
        half4v pf0[2], pf1[2];
        #pragma unroll
        for (int js = 0; js < 2; ++js) {
            float e0 = __expf(sf0[js][0]-mf0), e1 = __expf(sf0[js][1]-mf0);
            float e2 = __expf(sf0[js][2]-mf0), e3 = __expf(sf0[js][3]-mf0);
            l0 += (e0+e1)+(e2+e3);
            half4v p; p[0]=(_Float16)e0; p[1]=(_Float16)e1; p[2]=(_Float16)e2; p[3]=(_Float16)e3;
            pf0[js] = p;
            float f0 = __expf(sf1[js][0]-mf1), f1 = __expf(sf1[js][1]-mf1);
            float f2 = __expf(sf1[js][2]-mf1), f3 = __expf(sf1[js][3]-mf1);
            l1 += (f0+f1)+(f2+f3);
            half4v q; q[0]=(_Float16)f0; q[1]=(_Float16)f1; q[2]=(_Float16)f2; q[3]=(_Float16)f3;
            pf1[js] = q;
        }
        #pragma unroll
        for (int ct = 0; ct < 8; ++ct) {
            half4v vlo = __builtin_shufflevector(vf[ct], vf[ct], 0, 1, 2, 3);
            half4v vhi = __builtin_shufflevector(vf[ct], vf[ct], 4, 5, 6, 7);
            acc[ct][0] = __builtin_amdgcn_mfma_f32_16x16x16f16(vlo, pf0[0], acc[ct][0], 0, 0, 0);
            acc[ct][1] = __builtin_amdgcn_mfma_f32_16x16x16f16(vlo, pf1[0], acc[ct][1], 0, 0, 0);
            acc[ct][0] = __builtin_amdgcn_mfma_f32_16x16x16f16(vhi, pf0[1], acc[ct][0], 0, 0, 0);
            acc[ct][1] = __builtin_amdgcn_mfma_f32_16x16x16f16(vhi, pf1[1], acc[ct][1], 0, 0, 0);
        }
    };

    const int jb = wj * 2048;
    kl2(kA, jb);
    vl8(vA, jb);
    #pragma unroll 1
    for (int s2 = 0; s2 < 32; ++s2) {
        const int j0 = jb + s2*64;
        step(kA, vA, kB, vB, j0, true);
        step(kB, vB, kA, vA, j0 + 32, s2 < 31);
    }

    // ---- epilogue: l-sum over wj pair + single-round acc reduction ----
    l0 += __shfl_xor(l0, 16); l0 += __shfl_xor(l0, 32);
    l1 += __shfl_xor(l1, 16); l1 += __shfl_xor(l1, 32);
    if (lane < 32) s_lp[w*32 + lane] = (lane < 16) ? l0 : l1;

    const int kx = (lane & 7) << 2;   // XOR swizzle keeps b128 16B-aligned
    if (wj == 0) {
        #pragma unroll
        for (int t2 = 0; t2 < 4; ++t2) {
            *(f32x4*)&s_red[w][lane][(t2*8)     ^ kx] = acc[4 + t2][0];
            *(f32x4*)&s_red[w][lane][(t2*8 + 4) ^ kx] = acc[4 + t2][1];
        }
    } else {
        #pragma unroll
        for (int t2 = 0; t2 < 4; ++t2) {
            *(f32x4*)&s_red[w][lane][(t2*8)     ^ kx] = acc[t2][0];
            *(f32x4*)&s_red[w][lane][(t2*8 + 4) ^ kx] = acc[t2][1];
        }
    }
    __syncthreads();

    const float lt0 = s_lp[wc*32 + l15]      + s_lp[64 + wc*32 + l15];
    const float lt1 = s_lp[wc*32 + 16 + l15] + s_lp[64 + wc*32 + 16 + l15];
    const float g = gma[0];
    const float sc0 = g / lt0, sc1 = g / lt1;
    const int wp = w ^ 2;

    if (wj == 0) {
        #pragma unroll
        for (int t2 = 0; t2 < 4; ++t2) {
            f32x4 r0 = *(const f32x4*)&s_red[wp][lane][(t2*8)     ^ kx];
            f32x4 r1 = *(const f32x4*)&s_red[wp][lane][(t2*8 + 4) ^ kx];
            r0 += acc[t2][0];
            r1 += acc[t2][1];
            const int cb0 = (wc*8 + t2)*16 + quad*4;
            #pragma unroll
            for (int r4 = 0; r4 < 4; ++r4) {
                const size_t idx = ((size_t)(b*C_ + cb0 + r4)) * N_ + i0 + l15;
                out[idx]      = r0[r4] * sc0 + sem[idx];
                out[idx + 16] = r1[r4] * sc1 + sem[idx + 16];
            }
        }
    } else {
        #pragma unroll
        for (int t2 = 0; t2 < 4; ++t2) {
            f32x4 r0 = *(const f32x4*)&s_red[wp][lane][(t2*8)     ^ kx];
            f32x4 r1 = *(const f32x4*)&s_red[wp][lane][(t2*8 + 4) ^ kx];
            r0 += acc[4 + t2][0];
            r1 += acc[4 + t2][1];
            const int cb0 = (wc*8 + 4 + t2)*16 + quad*4;
            #pragma unroll
            for (int r4 = 0; r4 < 4; ++r4) {
                const size_t idx = ((size_t)(b*C_ + cb0 + r4)) * N_ + i0 + l15;
                out[idx]      = r0[r4] * sc0 + sem[idx];
                out[idx + 16] = r1[r4] * sc1 + sem[idx + 16];
            }
        }
    }
}

extern "C" void kernel_launch(void* const* d_in, const int* in_sizes, int n_in,
                              void* d_out, int out_size, void* d_ws, size_t ws_size,
                              hipStream_t stream) {
    const float* sem = (const float*)d_in[0];
    const float* str = (const float*)d_in[1];
    const float* Wq  = (const float*)d_in[2];
    const float* bq  = (const float*)d_in[3];
    const float* Wk  = (const float*)d_in[4];
    const float* bk  = (const float*)d_in[5];
    const float* Wv  = (const float*)d_in[6];
    const float* bv  = (const float*)d_in[7];
    const float* gma = (const float*)d_in[8];
    float* out = (float*)d_out;

    // Workspace (f16): Qh 1MB | Kh 1MB | Vh2 8MB | Wh 160KB
    _Float16* Qh  = (_Float16*)d_ws;
    _Float16* Kh  = Qh + (size_t)B_*N_*D_;
    _Float16* Vh2 = Kh + (size_t)B_*N_*D_;
    _Float16* Wh  = Vh2 + (size_t)B_*C_*N_;

    hipLaunchKernelGGL(wcvt_kernel, dim3(320), dim3(256), 0, stream, Wq, Wk, Wv, Wh);
    hipLaunchKernelGGL(proj_kernel, dim3(B_*(N_/64)*2), dim3(256), 0, stream,
                       sem, str, Wh, bq, bk, bv, Qh, Kh, Vh2);
    hipLaunchKernelGGL(flash_kernel, dim3(B_*(N_/32)), dim3(256), 0, stream,
                       Qh, Kh, Vh2, sem, gma, out);
}

// Round 4
// 157.074 us; speedup vs baseline: 1.2552x; 1.0819x over previous
//
#include <hip/hip_runtime.h>

// Problem constants
#define B_   4
#define C_   256
#define N_   4096   // H*W
#define D_   32     // qk projection dim
#define CP   264    // proj s_x row stride (halves): 256 + 8

typedef _Float16 half8  __attribute__((ext_vector_type(8)));
typedef _Float16 half4v __attribute__((ext_vector_type(4)));
typedef _Float16 half2v __attribute__((ext_vector_type(2)));
typedef float    f32x4  __attribute__((ext_vector_type(4)));

// ---------------------------------------------------------------------------
// Kernel 0: convert W (f32) -> Wh (f16), A-frag layout:
// Wh[((t*8+kc)*16 + row)*32 + kk] = W_t[row][kc*32+kk], t: 0-1 q, 2-3 k, 4-19 v
// ---------------------------------------------------------------------------
__global__ __launch_bounds__(256) void wcvt_kernel(
    const float* __restrict__ Wq, const float* __restrict__ Wk,
    const float* __restrict__ Wv, _Float16* __restrict__ Wh)
{
    const int idx = blockIdx.x * 256 + threadIdx.x;
    const int kk  = idx & 31;
    const int row = (idx >> 5) & 15;
    const int kc  = (idx >> 9) & 7;
    const int t   = idx >> 12;
    const int c   = kc*32 + kk;
    float v;
    if (t < 2)      v = Wq[(t*16 + row)*C_ + c];
    else if (t < 4) v = Wk[((t-2)*16 + row)*C_ + c];
    else            v = Wv[((t-4)*16 + row)*C_ + c];
    Wh[idx] = (_Float16)v;
}

// ---------------------------------------------------------------------------
// Kernel 1: projections v3 — merged-h 512-thread blocks.
// One block per 64-n tile stages BOTH maps ONCE (str was fetched 2x before).
// 8 waves cover all 20 t's (w<4: 3 t's, else 2). Wh A-frags double-buffered
// across kc to cover L2 latency. V epilogue: per-wave LDS transpose so the
// Vh2 frag layout is stored as coalesced dwordx4 (was 2B scalar scatter —
// the dominant proj cost).
// Vh2 layout (flash 16B/lane V loads): Vh2[b][jc2*8192 + ctg*512 + lr*8 +
//   js*4 + e] = V[c = ctg*16 + (lr&15)][j = jc2*32 + js*16 + (lr>>4)*4 + e]
// ---------------------------------------------------------------------------
__global__ __launch_bounds__(512, 2) void proj_kernel(
    const float* __restrict__ sem, const float* __restrict__ str,
    const _Float16* __restrict__ Wh,
    const float* __restrict__ bq, const float* __restrict__ bk,
    const float* __restrict__ bv,
    _Float16* __restrict__ Qh, _Float16* __restrict__ Kh, _Float16* __restrict__ Vh2)
{
    __shared__ __align__(16) _Float16 s_x[64 * CP];      // structural, 33 KB
    __shared__ __align__(16) _Float16 s_s[64 * CP];      // semantic,   33 KB
    __shared__ __align__(16) _Float16 s_v[8][3][1024];   // V transpose, 48 KB

    const int bid = blockIdx.x;
    const int nt6 = bid & 63;
    const int b   = bid >> 6;
    const int n0  = nt6 * 64;
    const int tid = threadIdx.x;
    const int w    = tid >> 6;       // 0..7
    const int lane = tid & 63;
    const int quad = lane >> 4;
    const int l15  = lane & 15;

    const int cnt = (w < 4) ? 3 : 2;
    const int t0  = (w < 4) ? w*3 : 12 + (w-4)*2;

    f32x4 acc[3][4];
    #pragma unroll
    for (int i = 0; i < 3; ++i)
        #pragma unroll
        for (int j = 0; j < 4; ++j) { acc[i][j][0]=0.f; acc[i][j][1]=0.f; acc[i][j][2]=0.f; acc[i][j][3]=0.f; }

    const size_t xbase = (size_t)b * C_ * N_;

    // ---- stage both 64n x 256c tiles, then ONE barrier ----
    #pragma unroll
    for (int r = 0; r < 4; ++r) {
        const int slot = r*512 + tid;
        const int nq = slot & 15;        // n-quad
        const int cp = slot >> 4;        // c-pair 0..127
        const float* p0 = str + xbase + (size_t)(2*cp) * N_ + n0 + nq*4;
        const float4 a4 = *(const float4*)p0;
        const float4 b4 = *(const float4*)(p0 + N_);
        #pragma unroll
        for (int t = 0; t < 4; ++t) {
            half2v hp; hp[0] = (_Float16)a4[t]; hp[1] = (_Float16)b4[t];
            *(half2v*)(s_x + (nq*4 + t)*CP + 2*cp) = hp;
        }
        const float* p1 = sem + xbase + (size_t)(2*cp) * N_ + n0 + nq*4;
        const float4 c4 = *(const float4*)p1;
        const float4 d4 = *(const float4*)(p1 + N_);
        #pragma unroll
        for (int t = 0; t < 4; ++t) {
            half2v hp; hp[0] = (_Float16)c4[t]; hp[1] = (_Float16)d4[t];
            *(half2v*)(s_s + (nq*4 + t)*CP + 2*cp) = hp;
        }
    }
    __syncthreads();

    // ---- compute: Wh A-frags double-buffered across kc ----
    auto afload = [&](half8 (&af)[3], int kc) {
        #pragma unroll
        for (int mi = 0; mi < 3; ++mi)
            if (mi < cnt)
                af[mi] = *(const half8*)(Wh + ((size_t)(((t0+mi)*8 + kc)*16 + l15))*32 + quad*8);
    };
    auto bload = [&](half8 (&bfr)[4], half8 (&sfr)[4], int kc) {
        #pragma unroll
        for (int nt = 0; nt < 4; ++nt)
            bfr[nt] = *(const half8*)(s_x + (nt*16 + l15)*CP + kc*32 + quad*8);
        if (w == 0) {
            #pragma unroll
            for (int nt = 0; nt < 4; ++nt)
                sfr[nt] = *(const half8*)(s_s + (nt*16 + l15)*CP + kc*32 + quad*8);
        }
    };
    auto domfma = [&](const half8 (&af)[3], const half8 (&bfr)[4], const half8 (&sfr)[4]) {
        #pragma unroll
        for (int mi = 0; mi < 3; ++mi) {
            if (mi >= cnt) break;
            const bool useS = (t0 + mi) < 2;   // q uses semantic
            #pragma unroll
            for (int nt = 0; nt < 4; ++nt)
                acc[mi][nt] = __builtin_amdgcn_mfma_f32_16x16x32_f16(
                                  af[mi], useS ? sfr[nt] : bfr[nt], acc[mi][nt], 0, 0, 0);
        }
    };

    half8 afA[3], afB[3];
    afload(afA, 0);
    #pragma unroll 1
    for (int kc2 = 0; kc2 < 4; ++kc2) {
        const int kc = kc2*2;
        half8 bfr[4], sfr[4];
        bload(bfr, sfr, kc);
        afload(afB, kc+1);
        domfma(afA, bfr, sfr);
        half8 bfr2[4], sfr2[4];
        bload(bfr2, sfr2, kc+1);
        if (kc2 < 3) afload(afA, kc+2);
        domfma(afB, bfr2, sfr2);
    }

    // ---- epilogue: bias + store. q/k direct; v via per-wave LDS transpose ----
    #pragma unroll
    for (int mi = 0; mi < 3; ++mi) {
        if (mi >= cnt) break;
        const int t = t0 + mi;
        if (t < 4) {
            const bool isq = (t < 2);
            const int  tt  = isq ? t : (t - 2);
            f32x4 b4 = *(const f32x4*)((isq ? bq : bk) + tt*16 + quad*4);
            _Float16* dst = isq ? Qh : Kh;
            const int dc  = tt*2 + (quad >> 1);
            const int off = (quad & 1) * 4;
            #pragma unroll
            for (int nt = 0; nt < 4; ++nt) {
                const int n = n0 + nt*16 + l15;
                f32x4 a = acc[mi][nt];
                half4v hq;
                hq[0]=(_Float16)(a[0]+b4[0]); hq[1]=(_Float16)(a[1]+b4[1]);
                hq[2]=(_Float16)(a[2]+b4[2]); hq[3]=(_Float16)(a[3]+b4[3]);
                *(half4v*)(dst + ((size_t)(b*4 + dc) * N_ + n) * 8 + off) = hq;
            }
        } else {
            const int ctg = t - 4;
            f32x4 b4 = *(const f32x4*)(bv + ctg*16 + quad*4);
            #pragma unroll
            for (int nt = 0; nt < 4; ++nt) {
                const int js = nt & 1;
                const int hb = nt >> 1;
                f32x4 a = acc[mi][nt];
                #pragma unroll
                for (int r = 0; r < 4; ++r)
                    s_v[w][mi][hb*512 + ((l15>>2)*16 + quad*4 + r)*8 + js*4 + (l15&3)]
                        = (_Float16)(a[r] + b4[r]);
            }
        }
    }
    // coalesced V stores (per-wave scratch, no barrier needed)
    {
        _Float16* vb = Vh2 + (size_t)b * (size_t)N_ * C_;
        const int jc2_0 = n0 >> 5;
        #pragma unroll
        for (int mi = 0; mi < 3; ++mi) {
            if (mi >= cnt) break;
            const int t = t0 + mi;
            if (t >= 4) {
                const int ctg = t - 4;
                #pragma unroll
                for (int hb = 0; hb < 2; ++hb) {
                    half8 vv = *(const half8*)(&s_v[w][mi][hb*512 + lane*8]);
                    *(half8*)(vb + (size_t)(jc2_0 + hb)*8192 + (size_t)ctg*512 + lane*8) = vv;
                }
            }
        }
    }
}

// ---------------------------------------------------------------------------
// Kernel 2: flash attention v8 — (j x c) wave split, PV upgraded to
// 16x16x32. The concat P half8 (two 16-j half4 frags) has per-lane j-order
// j = (e>>2)*16 + quad*4 + (e&3) — exactly Vh2's half8 element order, so
// both MFMA operands agree on the k-slot permutation and PV needs 8 x32
// MFMAs/step (was 32 x16: ~2.8x fewer MFMA cycles). cvt_pkrtz packing for
// P; setprio(1) around the PV cluster.
// ---------------------------------------------------------------------------
__global__ __launch_bounds__(256, 2) void flash_kernel(
    const _Float16* __restrict__ Qh, const _Float16* __restrict__ Kh,
    const _Float16* __restrict__ Vh2, const float* __restrict__ sem,
    const float* __restrict__ gma, float* __restrict__ out)
{
    __shared__ float s_mp[4*32];
    __shared__ float s_lp[4*32];
    __shared__ __align__(16) float s_red[4][64][32];   // 32 KB

    const int bid = blockIdx.x;
    const int b   = bid >> 7;
    const int i0  = (bid & 127) * 32;
    const int tid = threadIdx.x;
    const int w    = tid >> 6;
    const int lane = tid & 63;
    const int quad = lane >> 4;
    const int l15  = lane & 15;
    const int wc   = w & 1;
    const int wj   = w >> 1;

    // Q B-frags (persistent): B[k=d][n=i]
    const _Float16* qk_base = Qh + (size_t)(b*4 + quad) * N_ * 8;
    const half8 qf0 = *(const half8*)(qk_base + (size_t)(i0 + l15) * 8);
    const half8 qf1 = *(const half8*)(qk_base + (size_t)(i0 + 16 + l15) * 8);

    const _Float16* klane = Kh + ((size_t)(b*4 + quad) * N_ + l15) * 8;
    const _Float16* vl    = Vh2 + (size_t)b * (size_t)N_ * C_
                            + (size_t)(wc*8) * 512 + (size_t)lane * 8;

    // ---- phase 0: exact row max (wave w covers j in [w*1024, +1024)), K dbuf ----
    float mx0 = -3e38f, mx1 = -3e38f;
    {
        half8 kp[4], kn[4];
        auto kl4 = [&](half8 (&kf)[4], int j0) {
            #pragma unroll
            for (int js = 0; js < 4; ++js)
                kf[js] = *(const half8*)(klane + (size_t)(j0 + js*16) * 8);
        };
        auto p0step = [&](const half8 (&kf)[4], half8 (&kfn)[4], int j0, bool more) {
            if (more) kl4(kfn, j0 + 64);
            #pragma unroll
            for (int js = 0; js < 4; ++js) {
                f32x4 z; z[0]=0.f; z[1]=0.f; z[2]=0.f; z[3]=0.f;
                f32x4 s0 = __builtin_amdgcn_mfma_f32_16x16x32_f16(kf[js], qf0, z, 0, 0, 0);
                f32x4 s1 = __builtin_amdgcn_mfma_f32_16x16x32_f16(kf[js], qf1, z, 0, 0, 0);
                #pragma unroll
                for (int r = 0; r < 4; ++r) { mx0 = fmaxf(mx0, s0[r]); mx1 = fmaxf(mx1, s1[r]); }
            }
        };
        kl4(kp, w*1024);
        #pragma unroll 1
        for (int it2 = 0; it2 < 8; ++it2) {
            const int j0 = w*1024 + it2*128;
            p0step(kp, kn, j0, true);
            p0step(kn, kp, j0 + 64, it2 < 7);
        }
    }
    mx0 = fmaxf(mx0, __shfl_xor(mx0, 16)); mx0 = fmaxf(mx0, __shfl_xor(mx0, 32));
    mx1 = fmaxf(mx1, __shfl_xor(mx1, 16)); mx1 = fmaxf(mx1, __shfl_xor(mx1, 32));
    if (lane < 32) s_mp[w*32 + lane] = (lane < 16) ? mx0 : mx1;
    __syncthreads();
    float mf0 = -3e38f, mf1 = -3e38f;
    #pragma unroll
    for (int ww = 0; ww < 4; ++ww) {
        mf0 = fmaxf(mf0, s_mp[ww*32 + l15]);
        mf1 = fmaxf(mf1, s_mp[ww*32 + 16 + l15]);
    }

    // ---- main loop: j in [wj*2048, +2048), c-tiles [wc*8, +8) ----
    f32x4 acc[8][2];
    #pragma unroll
    for (int ct = 0; ct < 8; ++ct)
        #pragma unroll
        for (int f = 0; f < 2; ++f) { acc[ct][f][0]=0.f; acc[ct][f][1]=0.f; acc[ct][f][2]=0.f; acc[ct][f][3]=0.f; }
    float l0 = 0.f, l1 = 0.f;

    half8 kA[2], kB[2], vA[8], vB[8];

    auto kl2 = [&](half8 (&kf)[2], int j0) {
        kf[0] = *(const half8*)(klane + (size_t)j0 * 8);
        kf[1] = *(const half8*)(klane + (size_t)(j0 + 16) * 8);
    };
    auto vl8 = [&](half8 (&vf)[8], int j0) {
        const _Float16* p = vl + (size_t)(j0 >> 5) * 8192;
        #pragma unroll
        for (int ct = 0; ct < 8; ++ct)
            vf[ct] = *(const half8*)(p + ct*512);
    };
    auto mkp = [](const f32x4& s, float mf, float& lacc) -> half4v {
        float e0 = __expf(s[0]-mf), e1 = __expf(s[1]-mf);
        float e2 = __expf(s[2]-mf), e3 = __expf(s[3]-mf);
        lacc += (e0+e1)+(e2+e3);
        half2v p01 = __builtin_bit_cast(half2v, __builtin_amdgcn_cvt_pkrtz(e0, e1));
        half2v p23 = __builtin_bit_cast(half2v, __builtin_amdgcn_cvt_pkrtz(e2, e3));
        return __builtin_shufflevector(p01, p23, 0, 1, 2, 3);
    };

    auto step = [&](const half8 (&kf)[2], const half8 (&vf)[8],
                    half8 (&kfn)[2], half8 (&vfn)[8], int j0, bool more) {
        f32x4 z; z[0]=0.f; z[1]=0.f; z[2]=0.f; z[3]=0.f;
        f32x4 sf0[2], sf1[2];
        #pragma unroll
        for (int js = 0; js < 2; ++js) {
            sf0[js] = __builtin_amdgcn_mfma_f32_16x16x32_f16(kf[js], qf0, z, 0, 0, 0);
            sf1[js] = __builtin_amdgcn_mfma_f32_16x16x32_f16(kf[js], qf1, z, 0, 0, 0);
        }
        if (more) {                       // full-step-ahead prefetch
            kl2(kfn, j0 + 32);
            vl8(vfn, j0 + 32);
        }
        half4v pa0 = mkp(sf0[0], mf0, l0);
        half4v pb0 = mkp(sf0[1], mf0, l0);
        half4v pa1 = mkp(sf1[0], mf1, l1);
        half4v pb1 = mkp(sf1[1], mf1, l1);
        half8 pcat0 = __builtin_shufflevector(pa0, pb0, 0, 1, 2, 3, 4, 5, 6, 7);
        half8 pcat1 = __builtin_shufflevector(pa1, pb1, 0, 1, 2, 3, 4, 5, 6, 7);
        __builtin_amdgcn_s_setprio(1);
        #pragma unroll
        for (int ct = 0; ct < 8; ++ct) {
            acc[ct][0] = __builtin_amdgcn_mfma_f32_16x16x32_f16(vf[ct], pcat0, acc[ct][0], 0, 0, 0);
            acc[ct][1] = __builtin_amdgcn_mfma_f32_16x16x32_f16(vf[ct], pcat1, acc[ct][1], 0, 0, 0);
        }
        __builtin_amdgcn_s_setprio(0);
    };

    const int jb = wj * 2048;
    kl2(kA, jb);
    vl8(vA, jb);
    #pragma unroll 1
    for (int s2 = 0; s2 < 32; ++s2) {
        const int j0 = jb + s2*64;
        step(kA, vA, kB, vB, j0, true);
        step(kB, vB, kA, vA, j0 + 32, s2 < 31);
    }

    // ---- epilogue: l-sum over wj pair + single-round acc reduction ----
    l0 += __shfl_xor(l0, 16); l0 += __shfl_xor(l0, 32);
    l1 += __shfl_xor(l1, 16); l1 += __shfl_xor(l1, 32);
    if (lane < 32) s_lp[w*32 + lane] = (lane < 16) ? l0 : l1;

    const int kx = (lane & 7) << 2;   // XOR swizzle keeps b128 16B-aligned
    if (wj == 0) {
        #pragma unroll
        for (int t2 = 0; t2 < 4; ++t2) {
            *(f32x4*)&s_red[w][lane][(t2*8)     ^ kx] = acc[4 + t2][0];
            *(f32x4*)&s_red[w][lane][(t2*8 + 4) ^ kx] = acc[4 + t2][1];
        }
    } else {
        #pragma unroll
        for (int t2 = 0; t2 < 4; ++t2) {
            *(f32x4*)&s_red[w][lane][(t2*8)     ^ kx] = acc[t2][0];
            *(f32x4*)&s_red[w][lane][(t2*8 + 4) ^ kx] = acc[t2][1];
        }
    }
    __syncthreads();

    const float lt0 = s_lp[wc*32 + l15]      + s_lp[64 + wc*32 + l15];
    const float lt1 = s_lp[wc*32 + 16 + l15] + s_lp[64 + wc*32 + 16 + l15];
    const float g = gma[0];
    const float sc0 = g / lt0, sc1 = g / lt1;
    const int wp = w ^ 2;

    if (wj == 0) {
        #pragma unroll
        for (int t2 = 0; t2 < 4; ++t2) {
            f32x4 r0 = *(const f32x4*)&s_red[wp][lane][(t2*8)     ^ kx];
            f32x4 r1 = *(const f32x4*)&s_red[wp][lane][(t2*8 + 4) ^ kx];
            r0 += acc[t2][0];
            r1 += acc[t2][1];
            const int cb0 = (wc*8 + t2)*16 + quad*4;
            #pragma unroll
            for (int r4 = 0; r4 < 4; ++r4) {
                const size_t idx = ((size_t)(b*C_ + cb0 + r4)) * N_ + i0 + l15;
                out[idx]      = r0[r4] * sc0 + sem[idx];
                out[idx + 16] = r1[r4] * sc1 + sem[idx + 16];
            }
        }
    } else {
        #pragma unroll
        for (int t2 = 0; t2 < 4; ++t2) {
            f32x4 r0 = *(const f32x4*)&s_red[wp][lane][(t2*8)     ^ kx];
            f32x4 r1 = *(const f32x4*)&s_red[wp][lane][(t2*8 + 4) ^ kx];
            r0 += acc[4 + t2][0];
            r1 += acc[4 + t2][1];
            const int cb0 = (wc*8 + 4 + t2)*16 + quad*4;
            #pragma unroll
            for (int r4 = 0; r4 < 4; ++r4) {
                const size_t idx = ((size_t)(b*C_ + cb0 + r4)) * N_ + i0 + l15;
                out[idx]      = r0[r4] * sc0 + sem[idx];
                out[idx + 16] = r1[r4] * sc1 + sem[idx + 16];
            }
        }
    }
}

extern "C" void kernel_launch(void* const* d_in, const int* in_sizes, int n_in,
                              void* d_out, int out_size, void* d_ws, size_t ws_size,
                              hipStream_t stream) {
    const float* sem = (const float*)d_in[0];
    const float* str = (const float*)d_in[1];
    const float* Wq  = (const float*)d_in[2];
    const float* bq  = (const float*)d_in[3];
    const float* Wk  = (const float*)d_in[4];
    const float* bk  = (const float*)d_in[5];
    const float* Wv  = (const float*)d_in[6];
    const float* bv  = (const float*)d_in[7];
    const float* gma = (const float*)d_in[8];
    float* out = (float*)d_out;

    // Workspace (f16): Qh 1MB | Kh 1MB | Vh2 8MB | Wh 160KB
    _Float16* Qh  = (_Float16*)d_ws;
    _Float16* Kh  = Qh + (size_t)B_*N_*D_;
    _Float16* Vh2 = Kh + (size_t)B_*N_*D_;
    _Float16* Wh  = Vh2 + (size_t)B_*C_*N_;

    hipLaunchKernelGGL(wcvt_kernel, dim3(320), dim3(256), 0, stream, Wq, Wk, Wv, Wh);
    hipLaunchKernelGGL(proj_kernel, dim3(B_*(N_/64)), dim3(512), 0, stream,
                       sem, str, Wh, bq, bk, bv, Qh, Kh, Vh2);
    hipLaunchKernelGGL(flash_kernel, dim3(B_*(N_/32)), dim3(256), 0, stream,
                       Qh, Kh, Vh2, sem, gma, out);
}